// Round 1
// baseline (7266.835 us; speedup 1.0000x reference)
//
#include <hip/hip_runtime.h>
#include <math.h>

#define NPTS 8192
#define LGAB2 (-13.0f)   // log2(1/8192) == log(1/8192)*log2(e)

__device__ __forceinline__ float fexp2(float x){
#if __has_builtin(__builtin_amdgcn_exp2f)
  return __builtin_amdgcn_exp2f(x);
#else
  return exp2f(x);
#endif
}
__device__ __forceinline__ float flog2(float x){
#if __has_builtin(__builtin_amdgcn_logf)
  return __builtin_amdgcn_logf(x);
#else
  return log2f(x);
#endif
}

// Pack per-point data: (p0,p1,p2, |p|^2) and initial column packs (duals = 0).
__global__ __launch_bounds__(256) void ws_setup(
    const float* __restrict__ x, const float* __restrict__ y,
    float4* __restrict__ xp, float4* __restrict__ yp,
    float4* __restrict__ colpack, float inv0ce)
{
  int t = blockIdx.x * 256 + threadIdx.x;
  if (t >= NPTS) return;
  float x0 = x[3*t], x1 = x[3*t+1], x2 = x[3*t+2];
  float xs = x0*x0 + x1*x1 + x2*x2;
  float y0 = y[3*t], y1 = y[3*t+1], y2 = y[3*t+2];
  float ys = y0*y0 + y1*y1 + y2*y2;
  xp[t] = make_float4(x0,x1,x2,xs);
  yp[t] = make_float4(y0,y1,y2,ys);
  float hx = LGAB2 - 0.5f*xs*inv0ce;
  float hy = LGAB2 - 0.5f*ys*inv0ce;
  colpack[0*NPTS+t] = make_float4(y0,y1,y2,hy);  // ft: cols=y, h=log_b+g/eps (g=0)
  colpack[1*NPTS+t] = make_float4(x0,x1,x2,hx);  // gt: cols=x, h=log_a+f/eps (f=0)
  colpack[2*NPTS+t] = make_float4(x0,x1,x2,hx);  // pt: cols=x, h=log_a+pp/eps
  colpack[3*NPTS+t] = make_float4(y0,y1,y2,hy);  // qt: cols=y, h=log_b+qq/eps
}

// One phase: 4 softmins (ft,gt,pt,qt). Grid 512 blocks: s = b>>7 selects the
// softmin, 128 blocks x 64 rows each. lane = row, 4 waves split j into 4x2048.
// Epilogue (wave 0): LSE-merge across waves, update potential, write the
// column pack for the NEXT phase (double-buffered cps -> cpd).
// kind: 0 = assign (init), 1 = 0.5*(P+T) average (loop), 2 = final (write Tfin)
__global__ __launch_bounds__(256) void ws_softmin(
    const float4* __restrict__ xp, const float4* __restrict__ yp,
    const float4* __restrict__ cps, float4* __restrict__ cpd,
    float* __restrict__ P, float* __restrict__ Tfin,
    float ce, float eps_ln2, float inv_next_ce, int kind)
{
  int b = blockIdx.x;
  int s = b >> 7;
  int rowbase = (b & 127) << 6;
  int tid = threadIdx.x;
  int lane = tid & 63;
  int w = __builtin_amdgcn_readfirstlane(tid >> 6);  // force SGPR -> s_load cols

  const float4* rp = (s == 0 || s == 2) ? xp : yp;
  float4 rv = rp[rowbase + lane];
  float a0 = rv.x * ce, a1 = rv.y * ce, a2 = rv.z * ce;
  float hx = -0.5f * rv.w * ce;                      // row-constant, added at end
  const float4* cp = cps + s * NPTS;
  int j0 = w * 2048;

  // pass 1: exact row max of v = hy_j + (x'.y_j)  (base-2 exponent units)
  float m0 = -3.0e38f, m1 = -3.0e38f, m2 = -3.0e38f, m3 = -3.0e38f;
  #pragma unroll 2
  for (int j = j0; j < j0 + 2048; j += 4) {
    float4 Y0 = cp[j], Y1 = cp[j+1], Y2 = cp[j+2], Y3 = cp[j+3];
    float v0 = fmaf(a0, Y0.x, fmaf(a1, Y0.y, fmaf(a2, Y0.z, Y0.w)));
    float v1 = fmaf(a0, Y1.x, fmaf(a1, Y1.y, fmaf(a2, Y1.z, Y1.w)));
    float v2 = fmaf(a0, Y2.x, fmaf(a1, Y2.y, fmaf(a2, Y2.z, Y2.w)));
    float v3 = fmaf(a0, Y3.x, fmaf(a1, Y3.y, fmaf(a2, Y3.z, Y3.w)));
    m0 = fmaxf(m0, v0); m1 = fmaxf(m1, v1);
    m2 = fmaxf(m2, v2); m3 = fmaxf(m3, v3);
  }
  float m = fmaxf(fmaxf(m0, m1), fmaxf(m2, m3));

  // pass 2: sum of 2^(v - m)
  float s0 = 0.f, s1 = 0.f, s2 = 0.f, s3 = 0.f;
  #pragma unroll 2
  for (int j = j0; j < j0 + 2048; j += 4) {
    float4 Y0 = cp[j], Y1 = cp[j+1], Y2 = cp[j+2], Y3 = cp[j+3];
    float v0 = fmaf(a0, Y0.x, fmaf(a1, Y0.y, fmaf(a2, Y0.z, Y0.w - m)));
    float v1 = fmaf(a0, Y1.x, fmaf(a1, Y1.y, fmaf(a2, Y1.z, Y1.w - m)));
    float v2 = fmaf(a0, Y2.x, fmaf(a1, Y2.y, fmaf(a2, Y2.z, Y2.w - m)));
    float v3 = fmaf(a0, Y3.x, fmaf(a1, Y3.y, fmaf(a2, Y3.z, Y3.w - m)));
    s0 += fexp2(v0); s1 += fexp2(v1); s2 += fexp2(v2); s3 += fexp2(v3);
  }
  float ssum = (s0 + s1) + (s2 + s3);

  __shared__ float lm[4][64];
  __shared__ float lss[4][64];
  lm[w][lane] = m; lss[w][lane] = ssum;
  __syncthreads();

  if (tid < 64) {  // wave 0: its rv already holds row rowbase+lane data
    float M0 = lm[0][lane], M1 = lm[1][lane], M2 = lm[2][lane], M3 = lm[3][lane];
    float M = fmaxf(fmaxf(M0, M1), fmaxf(M2, M3));
    float S = lss[0][lane] * fexp2(M0 - M) + lss[1][lane] * fexp2(M1 - M)
            + lss[2][lane] * fexp2(M2 - M) + lss[3][lane] * fexp2(M3 - M);
    float T = -eps_ln2 * (hx + M + flog2(S));
    int row = rowbase + lane;
    if (kind == 2) {
      Tfin[s * NPTS + row] = T;
    } else {
      float* Pr = P + s * NPTS;
      float Pn = (kind == 0) ? T : 0.5f * (Pr[row] + T);
      Pr[row] = Pn;
      // f feeds gt's columns, g feeds ft's; pp/qq feed themselves.
      int dst = (s == 0) ? 1 : ((s == 1) ? 0 : s);
      float hy = LGAB2 + (Pn - 0.5f * rv.w) * inv_next_ce;
      cpd[dst * NPTS + row] = make_float4(rv.x, rv.y, rv.z, hy);
    }
  }
}

// loss = mean(f_fin - p_fin) + mean(g_fin - q_fin), fp64 accumulation
__global__ __launch_bounds__(256) void ws_reduce(
    const float* __restrict__ Tfin, float* __restrict__ out)
{
  int tid = threadIdx.x;
  double acc = 0.0;
  for (int i = tid; i < NPTS; i += 256) {
    acc += (double)Tfin[0*NPTS+i] - (double)Tfin[2*NPTS+i]
         + (double)Tfin[1*NPTS+i] - (double)Tfin[3*NPTS+i];
  }
  __shared__ double sd[256];
  sd[tid] = acc; __syncthreads();
  for (int k = 128; k > 0; k >>= 1) {
    if (tid < k) sd[tid] += sd[tid + k];
    __syncthreads();
  }
  if (tid == 0) out[0] = (float)(sd[0] / (double)NPTS);
}

extern "C" void kernel_launch(void* const* d_in, const int* in_sizes, int n_in,
                              void* d_out, int out_size, void* d_ws, size_t ws_size,
                              hipStream_t stream)
{
  const float* x = (const float*)d_in[0];
  const float* y = (const float*)d_in[1];
  float* out = (float*)d_out;

  char* wsp = (char*)d_ws;
  float4* xp  = (float4*)wsp;  wsp += (size_t)NPTS * 16;
  float4* yp  = (float4*)wsp;  wsp += (size_t)NPTS * 16;
  float4* cpA = (float4*)wsp;  wsp += (size_t)4 * NPTS * 16;
  float4* cpB = (float4*)wsp;  wsp += (size_t)4 * NPTS * 16;
  float*  P   = (float*)wsp;   wsp += (size_t)4 * NPTS * 4;
  float*  Tfin= (float*)wsp;   wsp += (size_t)4 * NPTS * 4;

  // geomloss epsilon schedule, replicated in f64 exactly as Python does it
  double epss[64]; int n = 0;
  double e = 4.0;                       // DIAMETER**P
  const double r = 0.9 * 0.9;          // SCALING**P
  const double target = 0.01 * 0.01;   // BLUR**P
  while (e > target && n < 60) { epss[n++] = e; e *= r; }   // n == 51
  int NPH = n + 2;                     // init + n loop iters + final

  const double L2E  = 1.4426950408889634;
  const double LN2d = 0.6931471805599453;

  float feps[64];
  feps[0] = (float)epss[0];                       // init uses eps_sched[0]
  for (int p = 1; p <= n; ++p) feps[p] = (float)epss[p-1];
  feps[n+1] = 1e-4f;                              // eps_final

  float inv0ce = (float)(L2E / (double)feps[0]);
  ws_setup<<<(NPTS + 255) / 256, 256, 0, stream>>>(x, y, xp, yp, cpA, inv0ce);

  for (int p = 0; p < NPH; ++p) {
    float epsf = feps[p];
    float ce = (float)(L2E / (double)epsf);
    float eps_ln2 = (float)((double)epsf * LN2d);
    float inv_next_ce = 0.f;
    if (p < NPH - 1) inv_next_ce = (float)(L2E / (double)feps[p+1]);
    int kind = (p == 0) ? 0 : ((p == NPH - 1) ? 2 : 1);
    const float4* src = (p & 1) ? cpB : cpA;
    float4*       dst = (p & 1) ? cpA : cpB;
    ws_softmin<<<512, 256, 0, stream>>>(xp, yp, src, dst, P, Tfin,
                                        ce, eps_ln2, inv_next_ce, kind);
  }

  ws_reduce<<<1, 256, 0, stream>>>(Tfin, out);
}

// Round 2
// 4608.621 us; speedup vs baseline: 1.5768x; 1.5768x over previous
//
#include <hip/hip_runtime.h>
#include <math.h>

#define NPTS 8192
#define LGAB2 (-13.0f)   // log2(1/8192) == log(1/8192)*log2(e)
#define NWAVE 16         // waves per block (1024 threads)

__device__ __forceinline__ float fexp2(float x){
#if __has_builtin(__builtin_amdgcn_exp2f)
  return __builtin_amdgcn_exp2f(x);
#else
  return exp2f(x);
#endif
}
__device__ __forceinline__ float flog2(float x){
#if __has_builtin(__builtin_amdgcn_logf)
  return __builtin_amdgcn_logf(x);
#else
  return log2f(x);
#endif
}

// Pack per-point data: (p0,p1,p2, |p|^2) and initial column packs (duals = 0).
__global__ __launch_bounds__(256) void ws_setup(
    const float* __restrict__ x, const float* __restrict__ y,
    float4* __restrict__ xp, float4* __restrict__ yp,
    float4* __restrict__ colpack, float inv0ce)
{
  int t = blockIdx.x * 256 + threadIdx.x;
  if (t >= NPTS) return;
  float x0 = x[3*t], x1 = x[3*t+1], x2 = x[3*t+2];
  float xs = x0*x0 + x1*x1 + x2*x2;
  float y0 = y[3*t], y1 = y[3*t+1], y2 = y[3*t+2];
  float ys = y0*y0 + y1*y1 + y2*y2;
  xp[t] = make_float4(x0,x1,x2,xs);
  yp[t] = make_float4(y0,y1,y2,ys);
  float hx = LGAB2 - 0.5f*xs*inv0ce;
  float hy = LGAB2 - 0.5f*ys*inv0ce;
  colpack[0*NPTS+t] = make_float4(y0,y1,y2,hy);  // ft: cols=y, h=log_b+g/eps (g=0)
  colpack[1*NPTS+t] = make_float4(x0,x1,x2,hx);  // gt: cols=x, h=log_a+f/eps (f=0)
  colpack[2*NPTS+t] = make_float4(x0,x1,x2,hx);  // pt: cols=x, h=log_a+pp/eps
  colpack[3*NPTS+t] = make_float4(y0,y1,y2,hy);  // qt: cols=y, h=log_b+qq/eps
}

// One phase: 4 softmins (ft,gt,pt,qt). Grid 512 blocks x 1024 threads:
// s = b>>7 selects the softmin, 128 blocks x 64 rows each. lane = row,
// 16 waves split j into 16x512 (2 blocks/CU -> 32 waves/CU, full occupancy).
// Epilogue (wave 0): LSE-merge across waves, update potential, write the
// column pack for the NEXT phase (double-buffered cps -> cpd).
// kind: 0 = assign (init), 1 = 0.5*(P+T) average (loop), 2 = final (write Tfin)
__global__ __launch_bounds__(1024) void ws_softmin(
    const float4* __restrict__ xp, const float4* __restrict__ yp,
    const float4* __restrict__ cps, float4* __restrict__ cpd,
    float* __restrict__ P, float* __restrict__ Tfin,
    float ce, float eps_ln2, float inv_next_ce, int kind)
{
  int b = blockIdx.x;
  int s = b >> 7;
  int rowbase = (b & 127) << 6;
  int tid = threadIdx.x;
  int lane = tid & 63;
  int w = __builtin_amdgcn_readfirstlane(tid >> 6);  // force SGPR -> s_load cols

  const float4* rp = (s == 0 || s == 2) ? xp : yp;
  float4 rv = rp[rowbase + lane];
  float a0 = rv.x * ce, a1 = rv.y * ce, a2 = rv.z * ce;
  float hx = -0.5f * rv.w * ce;                      // row-constant, added at end
  const float4* cp = cps + s * NPTS;
  int j0 = w * (NPTS / NWAVE);

  // pass 1: exact row max of v = hy_j + (x'.y_j)  (base-2 exponent units)
  float m0 = -3.0e38f, m1 = -3.0e38f, m2 = -3.0e38f, m3 = -3.0e38f;
  #pragma unroll 2
  for (int j = j0; j < j0 + NPTS / NWAVE; j += 4) {
    float4 Y0 = cp[j], Y1 = cp[j+1], Y2 = cp[j+2], Y3 = cp[j+3];
    float v0 = fmaf(a0, Y0.x, fmaf(a1, Y0.y, fmaf(a2, Y0.z, Y0.w)));
    float v1 = fmaf(a0, Y1.x, fmaf(a1, Y1.y, fmaf(a2, Y1.z, Y1.w)));
    float v2 = fmaf(a0, Y2.x, fmaf(a1, Y2.y, fmaf(a2, Y2.z, Y2.w)));
    float v3 = fmaf(a0, Y3.x, fmaf(a1, Y3.y, fmaf(a2, Y3.z, Y3.w)));
    m0 = fmaxf(m0, v0); m1 = fmaxf(m1, v1);
    m2 = fmaxf(m2, v2); m3 = fmaxf(m3, v3);
  }
  float m = fmaxf(fmaxf(m0, m1), fmaxf(m2, m3));

  // pass 2: sum of 2^(v - m)
  float s0 = 0.f, s1 = 0.f, s2 = 0.f, s3 = 0.f;
  #pragma unroll 2
  for (int j = j0; j < j0 + NPTS / NWAVE; j += 4) {
    float4 Y0 = cp[j], Y1 = cp[j+1], Y2 = cp[j+2], Y3 = cp[j+3];
    float v0 = fmaf(a0, Y0.x, fmaf(a1, Y0.y, fmaf(a2, Y0.z, Y0.w - m)));
    float v1 = fmaf(a0, Y1.x, fmaf(a1, Y1.y, fmaf(a2, Y1.z, Y1.w - m)));
    float v2 = fmaf(a0, Y2.x, fmaf(a1, Y2.y, fmaf(a2, Y2.z, Y2.w - m)));
    float v3 = fmaf(a0, Y3.x, fmaf(a1, Y3.y, fmaf(a2, Y3.z, Y3.w - m)));
    s0 += fexp2(v0); s1 += fexp2(v1); s2 += fexp2(v2); s3 += fexp2(v3);
  }
  float ssum = (s0 + s1) + (s2 + s3);

  __shared__ float lm[NWAVE][64];
  __shared__ float lss[NWAVE][64];
  lm[w][lane] = m; lss[w][lane] = ssum;
  __syncthreads();

  if (tid < 64) {  // wave 0: its rv already holds row rowbase+lane data
    float M = lm[0][lane];
    #pragma unroll
    for (int k = 1; k < NWAVE; ++k) M = fmaxf(M, lm[k][lane]);
    float S = 0.f;
    #pragma unroll
    for (int k = 0; k < NWAVE; ++k) S += lss[k][lane] * fexp2(lm[k][lane] - M);
    float T = -eps_ln2 * (hx + M + flog2(S));
    int row = rowbase + lane;
    if (kind == 2) {
      Tfin[s * NPTS + row] = T;
    } else {
      float* Pr = P + s * NPTS;
      float Pn = (kind == 0) ? T : 0.5f * (Pr[row] + T);
      Pr[row] = Pn;
      // f feeds gt's columns, g feeds ft's; pp/qq feed themselves.
      int dst = (s == 0) ? 1 : ((s == 1) ? 0 : s);
      float hy = LGAB2 + (Pn - 0.5f * rv.w) * inv_next_ce;
      cpd[dst * NPTS + row] = make_float4(rv.x, rv.y, rv.z, hy);
    }
  }
}

// loss = mean(f_fin - p_fin) + mean(g_fin - q_fin), fp64 accumulation
__global__ __launch_bounds__(256) void ws_reduce(
    const float* __restrict__ Tfin, float* __restrict__ out)
{
  int tid = threadIdx.x;
  double acc = 0.0;
  for (int i = tid; i < NPTS; i += 256) {
    acc += (double)Tfin[0*NPTS+i] - (double)Tfin[2*NPTS+i]
         + (double)Tfin[1*NPTS+i] - (double)Tfin[3*NPTS+i];
  }
  __shared__ double sd[256];
  sd[tid] = acc; __syncthreads();
  for (int k = 128; k > 0; k >>= 1) {
    if (tid < k) sd[tid] += sd[tid + k];
    __syncthreads();
  }
  if (tid == 0) out[0] = (float)(sd[0] / (double)NPTS);
}

extern "C" void kernel_launch(void* const* d_in, const int* in_sizes, int n_in,
                              void* d_out, int out_size, void* d_ws, size_t ws_size,
                              hipStream_t stream)
{
  const float* x = (const float*)d_in[0];
  const float* y = (const float*)d_in[1];
  float* out = (float*)d_out;

  char* wsp = (char*)d_ws;
  float4* xp  = (float4*)wsp;  wsp += (size_t)NPTS * 16;
  float4* yp  = (float4*)wsp;  wsp += (size_t)NPTS * 16;
  float4* cpA = (float4*)wsp;  wsp += (size_t)4 * NPTS * 16;
  float4* cpB = (float4*)wsp;  wsp += (size_t)4 * NPTS * 16;
  float*  P   = (float*)wsp;   wsp += (size_t)4 * NPTS * 4;
  float*  Tfin= (float*)wsp;   wsp += (size_t)4 * NPTS * 4;

  // geomloss epsilon schedule, replicated in f64 exactly as Python does it
  double epss[64]; int n = 0;
  double e = 4.0;                       // DIAMETER**P
  const double r = 0.9 * 0.9;          // SCALING**P
  const double target = 0.01 * 0.01;   // BLUR**P
  while (e > target && n < 60) { epss[n++] = e; e *= r; }   // n == 51
  int NPH = n + 2;                     // init + n loop iters + final

  const double L2E  = 1.4426950408889634;
  const double LN2d = 0.6931471805599453;

  float feps[64];
  feps[0] = (float)epss[0];                       // init uses eps_sched[0]
  for (int p = 1; p <= n; ++p) feps[p] = (float)epss[p-1];
  feps[n+1] = 1e-4f;                              // eps_final

  float inv0ce = (float)(L2E / (double)feps[0]);
  ws_setup<<<(NPTS + 255) / 256, 256, 0, stream>>>(x, y, xp, yp, cpA, inv0ce);

  for (int p = 0; p < NPH; ++p) {
    float epsf = feps[p];
    float ce = (float)(L2E / (double)epsf);
    float eps_ln2 = (float)((double)epsf * LN2d);
    float inv_next_ce = 0.f;
    if (p < NPH - 1) inv_next_ce = (float)(L2E / (double)feps[p+1]);
    int kind = (p == 0) ? 0 : ((p == NPH - 1) ? 2 : 1);
    const float4* src = (p & 1) ? cpB : cpA;
    float4*       dst = (p & 1) ? cpA : cpB;
    ws_softmin<<<512, 1024, 0, stream>>>(xp, yp, src, dst, P, Tfin,
                                         ce, eps_ln2, inv_next_ce, kind);
  }

  ws_reduce<<<1, 256, 0, stream>>>(Tfin, out);
}

// Round 4
// 4592.134 us; speedup vs baseline: 1.5825x; 1.0036x over previous
//
#include <hip/hip_runtime.h>
#include <math.h>

#define NPTS 8192
#define LGAB2 (-13.0f)   // log2(1/8192) == log(1/8192)*log2(e)
#define NWAVE 16         // waves per block (1024 threads)

// AS(4) = AMDGPU constant address space: uniform loads select s_load (SMEM,
// scalar K$) -> zero VALU address arithmetic in the inner loop. Hidden from
// the host compile pass (host C++ can't bind refs across address spaces).
#if defined(__HIP_DEVICE_COMPILE__)
#define CAS4 __attribute__((address_space(4)))
#else
#define CAS4
#endif
typedef const CAS4 float c4f;

__device__ __forceinline__ float fexp2(float x){
#if __has_builtin(__builtin_amdgcn_exp2f)
  return __builtin_amdgcn_exp2f(x);
#else
  return exp2f(x);
#endif
}
__device__ __forceinline__ float flog2(float x){
  return log2f(x);
}
__device__ __forceinline__ float fmax3(float a, float b, float c){
  return fmaxf(fmaxf(a, b), c);   // compiles to v_max3_f32 on gfx9+
}

// Pack per-point data: (p0,p1,p2, |p|^2) and initial column packs (duals = 0).
__global__ __launch_bounds__(256) void ws_setup(
    const float* __restrict__ x, const float* __restrict__ y,
    float4* __restrict__ xp, float4* __restrict__ yp,
    float4* __restrict__ colpack, float inv0ce)
{
  int t = blockIdx.x * 256 + threadIdx.x;
  if (t >= NPTS) return;
  float x0 = x[3*t], x1 = x[3*t+1], x2 = x[3*t+2];
  float xs = x0*x0 + x1*x1 + x2*x2;
  float y0 = y[3*t], y1 = y[3*t+1], y2 = y[3*t+2];
  float ys = y0*y0 + y1*y1 + y2*y2;
  xp[t] = make_float4(x0,x1,x2,xs);
  yp[t] = make_float4(y0,y1,y2,ys);
  float hx = LGAB2 - 0.5f*xs*inv0ce;
  float hy = LGAB2 - 0.5f*ys*inv0ce;
  colpack[0*NPTS+t] = make_float4(y0,y1,y2,hy);  // ft: cols=y, h=log_b+g/eps (g=0)
  colpack[1*NPTS+t] = make_float4(x0,x1,x2,hx);  // gt: cols=x, h=log_a+f/eps (f=0)
  colpack[2*NPTS+t] = make_float4(x0,x1,x2,hx);  // pt: cols=x, h=log_a+pp/eps
  colpack[3*NPTS+t] = make_float4(y0,y1,y2,hy);  // qt: cols=y, h=log_b+qq/eps
}

// One phase: 4 softmins (ft,gt,pt,qt). Grid 512 blocks x 1024 threads:
// s = b>>7 selects the softmin, 128 blocks x 64 rows each. lane = row,
// 16 waves split j into 16x512 (2 blocks/CU -> 32 waves/CU).
// Column data comes in via s_load (AS4, scalar floats merged to s_load_dwordxN
// by the backend) so the inner loop is pure VALU with <=1 SGPR operand per op.
// kind: 0 = assign (init), 1 = 0.5*(P+T) average (loop), 2 = final (write Tfin)
__global__ __launch_bounds__(1024) void ws_softmin(
    const float4* __restrict__ xp, const float4* __restrict__ yp,
    const float4* __restrict__ cps, float4* __restrict__ cpd,
    float* __restrict__ P, float* __restrict__ Tfin,
    float ce, float eps_ln2, float inv_next_ce, int kind)
{
  int b = blockIdx.x;
  int s = b >> 7;
  int rowbase = (b & 127) << 6;
  int tid = threadIdx.x;
  int lane = tid & 63;
  int w = __builtin_amdgcn_readfirstlane(tid >> 6);  // uniform wave id

  const float4* rp = (s == 0 || s == 2) ? xp : yp;
  float4 rv = rp[rowbase + lane];
  float a0 = rv.x * ce, a1 = rv.y * ce, a2 = rv.z * ce;
  float hx = -0.5f * rv.w * ce;                      // row-constant, added at end
  const c4f* cp = (const c4f*)(cps + s * NPTS);      // view as scalar floats
  int f0 = w * (NPTS / NWAVE) * 4;                   // float index of wave's chunk

  // pass 1: exact row max of v = hy_j + (x'.y_j)  (base-2 exponent units)
  float m0 = -3.0e38f, m1 = -3.0e38f;
  #pragma unroll 2
  for (int o = f0; o < f0 + (NPTS / NWAVE) * 4; o += 16) {
    float Y0x = cp[o+ 0], Y0y = cp[o+ 1], Y0z = cp[o+ 2], Y0w = cp[o+ 3];
    float Y1x = cp[o+ 4], Y1y = cp[o+ 5], Y1z = cp[o+ 6], Y1w = cp[o+ 7];
    float Y2x = cp[o+ 8], Y2y = cp[o+ 9], Y2z = cp[o+10], Y2w = cp[o+11];
    float Y3x = cp[o+12], Y3y = cp[o+13], Y3z = cp[o+14], Y3w = cp[o+15];
    float v0 = fmaf(a0, Y0x, fmaf(a1, Y0y, a2 * Y0z)) + Y0w;
    float v1 = fmaf(a0, Y1x, fmaf(a1, Y1y, a2 * Y1z)) + Y1w;
    float v2 = fmaf(a0, Y2x, fmaf(a1, Y2y, a2 * Y2z)) + Y2w;
    float v3 = fmaf(a0, Y3x, fmaf(a1, Y3y, a2 * Y3z)) + Y3w;
    m0 = fmax3(m0, v0, v1);
    m1 = fmax3(m1, v2, v3);
  }
  float m = fmaxf(m0, m1);

  // pass 2: sum of 2^(v - m)
  float s0 = 0.f, s1 = 0.f, s2 = 0.f, s3 = 0.f;
  #pragma unroll 2
  for (int o = f0; o < f0 + (NPTS / NWAVE) * 4; o += 16) {
    float Y0x = cp[o+ 0], Y0y = cp[o+ 1], Y0z = cp[o+ 2], Y0w = cp[o+ 3];
    float Y1x = cp[o+ 4], Y1y = cp[o+ 5], Y1z = cp[o+ 6], Y1w = cp[o+ 7];
    float Y2x = cp[o+ 8], Y2y = cp[o+ 9], Y2z = cp[o+10], Y2w = cp[o+11];
    float Y3x = cp[o+12], Y3y = cp[o+13], Y3z = cp[o+14], Y3w = cp[o+15];
    float u0 = fmaf(a0, Y0x, fmaf(a1, Y0y, fmaf(a2, Y0z, Y0w - m)));
    float u1 = fmaf(a0, Y1x, fmaf(a1, Y1y, fmaf(a2, Y1z, Y1w - m)));
    float u2 = fmaf(a0, Y2x, fmaf(a1, Y2y, fmaf(a2, Y2z, Y2w - m)));
    float u3 = fmaf(a0, Y3x, fmaf(a1, Y3y, fmaf(a2, Y3z, Y3w - m)));
    s0 += fexp2(u0); s1 += fexp2(u1); s2 += fexp2(u2); s3 += fexp2(u3);
  }
  float ssum = (s0 + s1) + (s2 + s3);

  __shared__ float lm[NWAVE][64];
  __shared__ float lss[NWAVE][64];
  lm[w][lane] = m; lss[w][lane] = ssum;
  __syncthreads();

  if (tid < 64) {  // wave 0: its rv already holds row rowbase+lane data
    float M = lm[0][lane];
    #pragma unroll
    for (int k = 1; k < NWAVE; ++k) M = fmaxf(M, lm[k][lane]);
    float S = 0.f;
    #pragma unroll
    for (int k = 0; k < NWAVE; ++k) S += lss[k][lane] * fexp2(lm[k][lane] - M);
    float T = -eps_ln2 * (hx + M + flog2(S));
    int row = rowbase + lane;
    if (kind == 2) {
      Tfin[s * NPTS + row] = T;
    } else {
      float* Pr = P + s * NPTS;
      float Pn = (kind == 0) ? T : 0.5f * (Pr[row] + T);
      Pr[row] = Pn;
      // f feeds gt's columns, g feeds ft's; pp/qq feed themselves.
      int dst = (s == 0) ? 1 : ((s == 1) ? 0 : s);
      float hy = LGAB2 + (Pn - 0.5f * rv.w) * inv_next_ce;
      cpd[dst * NPTS + row] = make_float4(rv.x, rv.y, rv.z, hy);
    }
  }
}

// loss = mean(f_fin - p_fin) + mean(g_fin - q_fin), fp64 accumulation
__global__ __launch_bounds__(256) void ws_reduce(
    const float* __restrict__ Tfin, float* __restrict__ out)
{
  int tid = threadIdx.x;
  double acc = 0.0;
  for (int i = tid; i < NPTS; i += 256) {
    acc += (double)Tfin[0*NPTS+i] - (double)Tfin[2*NPTS+i]
         + (double)Tfin[1*NPTS+i] - (double)Tfin[3*NPTS+i];
  }
  __shared__ double sd[256];
  sd[tid] = acc; __syncthreads();
  for (int k = 128; k > 0; k >>= 1) {
    if (tid < k) sd[tid] += sd[tid + k];
    __syncthreads();
  }
  if (tid == 0) out[0] = (float)(sd[0] / (double)NPTS);
}

extern "C" void kernel_launch(void* const* d_in, const int* in_sizes, int n_in,
                              void* d_out, int out_size, void* d_ws, size_t ws_size,
                              hipStream_t stream)
{
  const float* x = (const float*)d_in[0];
  const float* y = (const float*)d_in[1];
  float* out = (float*)d_out;

  char* wsp = (char*)d_ws;
  float4* xp  = (float4*)wsp;  wsp += (size_t)NPTS * 16;
  float4* yp  = (float4*)wsp;  wsp += (size_t)NPTS * 16;
  float4* cpA = (float4*)wsp;  wsp += (size_t)4 * NPTS * 16;
  float4* cpB = (float4*)wsp;  wsp += (size_t)4 * NPTS * 16;
  float*  P   = (float*)wsp;   wsp += (size_t)4 * NPTS * 4;
  float*  Tfin= (float*)wsp;   wsp += (size_t)4 * NPTS * 4;

  // geomloss epsilon schedule, replicated in f64 exactly as Python does it
  double epss[64]; int n = 0;
  double e = 4.0;                       // DIAMETER**P
  const double r = 0.9 * 0.9;          // SCALING**P
  const double target = 0.01 * 0.01;   // BLUR**P
  while (e > target && n < 60) { epss[n++] = e; e *= r; }   // n == 51
  int NPH = n + 2;                     // init + n loop iters + final

  const double L2E  = 1.4426950408889634;
  const double LN2d = 0.6931471805599453;

  float feps[64];
  feps[0] = (float)epss[0];                       // init uses eps_sched[0]
  for (int p = 1; p <= n; ++p) feps[p] = (float)epss[p-1];
  feps[n+1] = 1e-4f;                              // eps_final

  float inv0ce = (float)(L2E / (double)feps[0]);
  ws_setup<<<(NPTS + 255) / 256, 256, 0, stream>>>(x, y, xp, yp, cpA, inv0ce);

  for (int p = 0; p < NPH; ++p) {
    float epsf = feps[p];
    float ce = (float)(L2E / (double)epsf);
    float eps_ln2 = (float)((double)epsf * LN2d);
    float inv_next_ce = 0.f;
    if (p < NPH - 1) inv_next_ce = (float)(L2E / (double)feps[p+1]);
    int kind = (p == 0) ? 0 : ((p == NPH - 1) ? 2 : 1);
    const float4* src = (p & 1) ? cpB : cpA;
    float4*       dst = (p & 1) ? cpA : cpB;
    ws_softmin<<<512, 1024, 0, stream>>>(xp, yp, src, dst, P, Tfin,
                                         ce, eps_ln2, inv_next_ce, kind);
  }

  ws_reduce<<<1, 256, 0, stream>>>(Tfin, out);
}

// Round 5
// 3534.557 us; speedup vs baseline: 2.0559x; 1.2992x over previous
//
#include <hip/hip_runtime.h>
#include <math.h>

#define NPTS 8192
#define LGAB2 (-13.0f)   // log2(1/8192) == log(1/8192)*log2(e)
#define NWAVE 16         // waves per block (1024 threads)

typedef __attribute__((ext_vector_type(2))) float f2;

__device__ __forceinline__ float fexp2(float x){
#if __has_builtin(__builtin_amdgcn_exp2f)
  return __builtin_amdgcn_exp2f(x);
#else
  return exp2f(x);
#endif
}
__device__ __forceinline__ f2 ffma2(f2 a, f2 b, f2 c){
  return __builtin_elementwise_fma(a, b, c);   // v_pk_fma_f32
}
__device__ __forceinline__ f2 fmax2(f2 a, f2 b){
  return __builtin_elementwise_max(a, b);      // v_pk_max_f32
}

// Column pack layout: pair-transposed. For columns (2p, 2p+1) of softmin slot s,
// float4[2p]   = (x_2p, x_2p+1, y_2p, y_2p+1)
// float4[2p+1] = (z_2p, z_2p+1, w_2p, w_2p+1)   where w = h-term.
// Two float4 loads give exactly the aligned VGPR pairs VOP3P wants.

// Pack per-point data: (p0,p1,p2, |p|^2) and initial column packs (duals = 0).
__global__ __launch_bounds__(256) void ws_setup(
    const float* __restrict__ x, const float* __restrict__ y,
    float4* __restrict__ xp, float4* __restrict__ yp,
    float4* __restrict__ colpack, float inv0ce)
{
  int t = blockIdx.x * 256 + threadIdx.x;
  if (t >= NPTS) return;
  float x0 = x[3*t], x1 = x[3*t+1], x2 = x[3*t+2];
  float xs = x0*x0 + x1*x1 + x2*x2;
  float y0 = y[3*t], y1 = y[3*t+1], y2 = y[3*t+2];
  float ys = y0*y0 + y1*y1 + y2*y2;
  xp[t] = make_float4(x0,x1,x2,xs);
  yp[t] = make_float4(y0,y1,y2,ys);
  float hx = LGAB2 - 0.5f*xs*inv0ce;
  float hy = LGAB2 - 0.5f*ys*inv0ce;
  int p = t >> 1, sub = t & 1;
  // slots: 0 -> y-cols (ft), 1 -> x-cols (gt), 2 -> x-cols (pt), 3 -> y-cols (qt)
  {
    float* c0 = (float*)(colpack + 0*NPTS);
    c0[p*8+sub] = y0; c0[p*8+2+sub] = y1; c0[p*8+4+sub] = y2; c0[p*8+6+sub] = hy;
    float* c3 = (float*)(colpack + 3*NPTS);
    c3[p*8+sub] = y0; c3[p*8+2+sub] = y1; c3[p*8+4+sub] = y2; c3[p*8+6+sub] = hy;
  }
  {
    float* c1 = (float*)(colpack + 1*NPTS);
    c1[p*8+sub] = x0; c1[p*8+2+sub] = x1; c1[p*8+4+sub] = x2; c1[p*8+6+sub] = hx;
    float* c2 = (float*)(colpack + 2*NPTS);
    c2[p*8+sub] = x0; c2[p*8+2+sub] = x1; c2[p*8+4+sub] = x2; c2[p*8+6+sub] = hx;
  }
}

// One phase: 4 softmins (ft,gt,pt,qt). Grid 512 blocks x 1024 threads:
// s = b>>7 selects the softmin, 128 blocks x 64 rows each. lane = row,
// 16 waves split j into 16x512 (2 blocks/CU -> 32 waves/CU).
// Inner loop in packed fp32 (2 columns per VOP3P op).
// kind: 0 = assign (init), 1 = 0.5*(P+T) average (loop), 2 = final (write Tfin)
__global__ __launch_bounds__(1024) void ws_softmin(
    const float4* __restrict__ xp, const float4* __restrict__ yp,
    const float4* __restrict__ cps, float4* __restrict__ cpd,
    float* __restrict__ P, float* __restrict__ Tfin,
    float ce, float eps_ln2, float inv_next_ce, int kind)
{
  int b = blockIdx.x;
  int s = b >> 7;
  int rowbase = (b & 127) << 6;
  int tid = threadIdx.x;
  int lane = tid & 63;
  int w = __builtin_amdgcn_readfirstlane(tid >> 6);  // uniform wave id

  const float4* rp = (s == 0 || s == 2) ? xp : yp;
  float4 rv = rp[rowbase + lane];
  float a0 = rv.x * ce, a1 = rv.y * ce, a2 = rv.z * ce;
  float hx = -0.5f * rv.w * ce;                      // row-constant, added at end
  const float4* cp = cps + (size_t)s * NPTS;
  f2 A0 = {a0, a0}, A1 = {a1, a1}, A2 = {a2, a2};
  int pb0 = w * (NPTS / NWAVE / 2);                  // 256 pair-blocks per wave

  // pass 1: exact row max of v = hy_j + (x'.y_j)  (base-2 exponent units)
  f2 mA = {-3.0e38f, -3.0e38f}, mB = mA;
  #pragma unroll 2
  for (int pb = pb0; pb < pb0 + NPTS / NWAVE / 2; pb += 2) {
    float4 P0 = cp[2*pb+0], Q0 = cp[2*pb+1];
    float4 P1 = cp[2*pb+2], Q1 = cp[2*pb+3];
    f2 X0 = {P0.x, P0.y}, Y0 = {P0.z, P0.w}, Z0 = {Q0.x, Q0.y}, W0 = {Q0.z, Q0.w};
    f2 X1 = {P1.x, P1.y}, Y1 = {P1.z, P1.w}, Z1 = {Q1.x, Q1.y}, W1 = {Q1.z, Q1.w};
    f2 t0 = ffma2(A2, Z0, W0);
    f2 t1 = ffma2(A2, Z1, W1);
    t0 = ffma2(A1, Y0, t0);
    t1 = ffma2(A1, Y1, t1);
    t0 = ffma2(A0, X0, t0);
    t1 = ffma2(A0, X1, t1);
    mA = fmax2(mA, t0);
    mB = fmax2(mB, t1);
  }
  f2 mAB = fmax2(mA, mB);
  float m = fmaxf(mAB.x, mAB.y);
  f2 M2 = {m, m};

  // pass 2: sum of 2^(v - m)
  f2 sA = {0.f, 0.f}, sB = sA;
  #pragma unroll 2
  for (int pb = pb0; pb < pb0 + NPTS / NWAVE / 2; pb += 2) {
    float4 P0 = cp[2*pb+0], Q0 = cp[2*pb+1];
    float4 P1 = cp[2*pb+2], Q1 = cp[2*pb+3];
    f2 X0 = {P0.x, P0.y}, Y0 = {P0.z, P0.w}, Z0 = {Q0.x, Q0.y}, W0 = {Q0.z, Q0.w};
    f2 X1 = {P1.x, P1.y}, Y1 = {P1.z, P1.w}, Z1 = {Q1.x, Q1.y}, W1 = {Q1.z, Q1.w};
    f2 u0 = ffma2(A2, Z0, W0 - M2);
    f2 u1 = ffma2(A2, Z1, W1 - M2);
    u0 = ffma2(A1, Y0, u0);
    u1 = ffma2(A1, Y1, u1);
    u0 = ffma2(A0, X0, u0);
    u1 = ffma2(A0, X1, u1);
    f2 e0, e1;
    e0.x = fexp2(u0.x); e0.y = fexp2(u0.y);
    e1.x = fexp2(u1.x); e1.y = fexp2(u1.y);
    sA += e0;
    sB += e1;
  }
  f2 sAB = sA + sB;
  float ssum = sAB.x + sAB.y;

  __shared__ float lm[NWAVE][64];
  __shared__ float lss[NWAVE][64];
  lm[w][lane] = m; lss[w][lane] = ssum;
  __syncthreads();

  if (tid < 64) {  // wave 0: its rv already holds row rowbase+lane data
    float M = lm[0][lane];
    #pragma unroll
    for (int k = 1; k < NWAVE; ++k) M = fmaxf(M, lm[k][lane]);
    float S = 0.f;
    #pragma unroll
    for (int k = 0; k < NWAVE; ++k) S += lss[k][lane] * fexp2(lm[k][lane] - M);
    float T = -eps_ln2 * (hx + M + log2f(S));
    int row = rowbase + lane;
    if (kind == 2) {
      Tfin[s * NPTS + row] = T;
    } else {
      float* Pr = P + s * NPTS;
      float Pn = (kind == 0) ? T : 0.5f * (Pr[row] + T);
      Pr[row] = Pn;
      // f feeds gt's columns, g feeds ft's; pp/qq feed themselves.
      int dst = (s == 0) ? 1 : ((s == 1) ? 0 : s);
      float hy = LGAB2 + (Pn - 0.5f * rv.w) * inv_next_ce;
      float* cd = (float*)(cpd + (size_t)dst * NPTS);
      int p = row >> 1, sub = row & 1;
      cd[p*8+sub]   = rv.x;
      cd[p*8+2+sub] = rv.y;
      cd[p*8+4+sub] = rv.z;
      cd[p*8+6+sub] = hy;
    }
  }
}

// loss = mean(f_fin - p_fin) + mean(g_fin - q_fin), fp64 accumulation
__global__ __launch_bounds__(256) void ws_reduce(
    const float* __restrict__ Tfin, float* __restrict__ out)
{
  int tid = threadIdx.x;
  double acc = 0.0;
  for (int i = tid; i < NPTS; i += 256) {
    acc += (double)Tfin[0*NPTS+i] - (double)Tfin[2*NPTS+i]
         + (double)Tfin[1*NPTS+i] - (double)Tfin[3*NPTS+i];
  }
  __shared__ double sd[256];
  sd[tid] = acc; __syncthreads();
  for (int k = 128; k > 0; k >>= 1) {
    if (tid < k) sd[tid] += sd[tid + k];
    __syncthreads();
  }
  if (tid == 0) out[0] = (float)(sd[0] / (double)NPTS);
}

extern "C" void kernel_launch(void* const* d_in, const int* in_sizes, int n_in,
                              void* d_out, int out_size, void* d_ws, size_t ws_size,
                              hipStream_t stream)
{
  const float* x = (const float*)d_in[0];
  const float* y = (const float*)d_in[1];
  float* out = (float*)d_out;

  char* wsp = (char*)d_ws;
  float4* xp  = (float4*)wsp;  wsp += (size_t)NPTS * 16;
  float4* yp  = (float4*)wsp;  wsp += (size_t)NPTS * 16;
  float4* cpA = (float4*)wsp;  wsp += (size_t)4 * NPTS * 16;
  float4* cpB = (float4*)wsp;  wsp += (size_t)4 * NPTS * 16;
  float*  P   = (float*)wsp;   wsp += (size_t)4 * NPTS * 4;
  float*  Tfin= (float*)wsp;   wsp += (size_t)4 * NPTS * 4;

  // geomloss epsilon schedule, replicated in f64 exactly as Python does it
  double epss[64]; int n = 0;
  double e = 4.0;                       // DIAMETER**P
  const double r = 0.9 * 0.9;          // SCALING**P
  const double target = 0.01 * 0.01;   // BLUR**P
  while (e > target && n < 60) { epss[n++] = e; e *= r; }   // n == 51
  int NPH = n + 2;                     // init + n loop iters + final

  const double L2E  = 1.4426950408889634;
  const double LN2d = 0.6931471805599453;

  float feps[64];
  feps[0] = (float)epss[0];                       // init uses eps_sched[0]
  for (int p = 1; p <= n; ++p) feps[p] = (float)epss[p-1];
  feps[n+1] = 1e-4f;                              // eps_final

  float inv0ce = (float)(L2E / (double)feps[0]);
  ws_setup<<<(NPTS + 255) / 256, 256, 0, stream>>>(x, y, xp, yp, cpA, inv0ce);

  for (int p = 0; p < NPH; ++p) {
    float epsf = feps[p];
    float ce = (float)(L2E / (double)epsf);
    float eps_ln2 = (float)((double)epsf * LN2d);
    float inv_next_ce = 0.f;
    if (p < NPH - 1) inv_next_ce = (float)(L2E / (double)feps[p+1]);
    int kind = (p == 0) ? 0 : ((p == NPH - 1) ? 2 : 1);
    const float4* src = (p & 1) ? cpB : cpA;
    float4*       dst = (p & 1) ? cpA : cpB;
    ws_softmin<<<512, 1024, 0, stream>>>(xp, yp, src, dst, P, Tfin,
                                         ce, eps_ln2, inv_next_ce, kind);
  }

  ws_reduce<<<1, 256, 0, stream>>>(Tfin, out);
}